// Round 6
// baseline (92.844 us; speedup 1.0000x reference)
//
#include <hip/hip_runtime.h>

#define B_ 4
#define C_ 256
#define C2_ 128
#define N_ 4096
#define SEG_ 4
#define TPS_ (N_ / 64 / SEG_)   // 16 KV tiles (64 rows) per segment
#define LOG2E_ 1.4426950408889634f
#define SHIFT2_ 43.28085122666891f   // 30 * log2(e); softmax in exp2 domain

typedef __bf16 bf16;
typedef __bf16 bf16x8 __attribute__((ext_vector_type(8)));
typedef __bf16 bf16x4 __attribute__((ext_vector_type(4)));
typedef __bf16 bf16x2 __attribute__((ext_vector_type(2)));
typedef float f32x4 __attribute__((ext_vector_type(4)));
typedef float f32x16 __attribute__((ext_vector_type(16)));
typedef unsigned int u32x4 __attribute__((ext_vector_type(4)));

__device__ __forceinline__ f32x4 mfma16(bf16x8 a, bf16x8 b, f32x4 c) {
  return __builtin_amdgcn_mfma_f32_16x16x32_bf16(a, b, c, 0, 0, 0);
}
__device__ __forceinline__ f32x16 mfma32(bf16x8 a, bf16x8 b, f32x16 c) {
  return __builtin_amdgcn_mfma_f32_32x32x16_bf16(a, b, c, 0, 0, 0);
}

__device__ __forceinline__ float fexp2(float x) {
#if __has_builtin(__builtin_amdgcn_exp2f)
  return __builtin_amdgcn_exp2f(x);
#else
  return exp2f(x);
#endif
}

// async global->LDS, 16B per lane (dest = wave-uniform base + lane*16)
typedef const __attribute__((address_space(1))) uint32_t* gas_ptr;
typedef __attribute__((address_space(3))) uint32_t* las_ptr;
__device__ __forceinline__ void gld_lds16(const bf16* g, bf16* l) {
  __builtin_amdgcn_global_load_lds((gas_ptr)g, (las_ptr)l, 16, 0, 0);
}

// pack two f32 -> one dword of 2 bf16
__device__ __forceinline__ uint32_t pk2(float a, float b) {
  bf16x2 v; v[0] = (bf16)a; v[1] = (bf16)b;
  return __builtin_bit_cast(uint32_t, v);
}
// v_permlane32_swap_b32: a[l>=32] <-> b[l<32]  (VALU cross-lane, no LDS pipe)
__device__ __forceinline__ void pl32swap(uint32_t& a, uint32_t& b) {
  asm volatile("v_permlane32_swap_b32 %0, %1" : "+v"(a), "+v"(b));
}

// exp2-domain softmax numerator + bf16 pack/transpose (l done via ones-MFMA)
__device__ __forceinline__ void exp_pack(const f32x16& s,
                                         bf16x8& pf0, bf16x8& pf1) {
  float p[16];
  #pragma unroll
  for (int r = 0; r < 16; ++r) p[r] = fexp2(s[r] - SHIFT2_);
  uint32_t A[4], Bb[4];
  #pragma unroll
  for (int G = 0; G < 4; ++G) {
    A[G]  = pk2(p[4 * G + 0], p[4 * G + 1]);
    Bb[G] = pk2(p[4 * G + 2], p[4 * G + 3]);
  }
  pl32swap(A[0], A[1]);  pl32swap(Bb[0], Bb[1]);
  { u32x4 dv = {A[0], Bb[0], A[1], Bb[1]}; pf0 = __builtin_bit_cast(bf16x8, dv); }
  pl32swap(A[2], A[3]);  pl32swap(Bb[2], Bb[3]);
  { u32x4 dv = {A[2], Bb[2], A[3], Bb[3]}; pf1 = __builtin_bit_cast(bf16x8, dv); }
}

// 32x32x16 fragment layouts:
//  A/B: lane = idx%32 + 32*((k%16)/8), elem = k%8 (8 bf16 / 4 VGPRs)
//  C/D: col = lane&31, row = (reg&3) + 8*(reg>>2) + 4*(lane>>5)
// Operand storage (fragment-major, wave reads = linear 1KB):
//  theta/phi: [b][n/32][ks 8][64][8]   (theta pre-scaled by log2e)
//  g (V^T):   [b][n/32 chunk][dtile 4][ks2 2][64][8] (8KB per 32-row chunk)

// ---------------------------------------------------------------------------
// Kernel 1: fused 3-way 1x1-conv projections, 32-row n-tiles (512 blocks ->
// 2+ blocks/CU vs previous 64-row/256-block 1/CU: latency-hiding for the
// memory-bound staging phase). Fragment-major outputs unchanged.
// ---------------------------------------------------------------------------
__global__ __launch_bounds__(256) void proj_kernel(
    const float* __restrict__ x,
    const float* __restrict__ w0, const float* __restrict__ b0,
    const float* __restrict__ w1, const float* __restrict__ b1,
    const float* __restrict__ w2, const float* __restrict__ b2,
    bf16* __restrict__ o0, bf16* __restrict__ o1, bf16* __restrict__ o2)
{
  __shared__ bf16 Xs[32][C_];   // [n][c], 16B block cb swizzled: cb ^= (n&7)
  const int tid  = threadIdx.x;
  const int lane = tid & 63;
  const int w    = tid >> 6;
  const int n0   = blockIdx.x * 32;
  const int b    = blockIdx.y;
  const int l15  = lane & 15;
  const int lg   = lane >> 4;
  const float* xb = x + (size_t)b * C_ * N_;

  // stage X^T: thread owns row n=lane&31; wave w covers c in [64w, 64w+64),
  // lane-half hh covers the 32-c half.
  {
    const int nl = lane & 31;
    const int hh = lane >> 5;
    #pragma unroll
    for (int g = 0; g < 4; ++g) {
      int c0 = w * 64 + hh * 32 + g * 8;
      bf16x8 h;
      #pragma unroll
      for (int i = 0; i < 8; ++i)
        h[i] = (bf16)xb[(size_t)(c0 + i) * N_ + n0 + nl];
      int cbs = (c0 >> 3) ^ (nl & 7);
      *(bf16x8*)&Xs[nl][cbs * 8] = h;
    }
  }
  __syncthreads();

  const f32x4 fzero = {0.f, 0.f, 0.f, 0.f};
  f32x4 acc[3][2][2];
  #pragma unroll
  for (int p = 0; p < 3; ++p)
    #pragma unroll
    for (int ot = 0; ot < 2; ++ot)
      #pragma unroll
      for (int nt = 0; nt < 2; ++nt) acc[p][ot][nt] = fzero;

  const float* Wp[3] = {w0, w1, w2};
  const int arow = w * 32 + l15;
  const int kbase = lg * 8;

  for (int kc = 0; kc < 8; ++kc) {
    bf16x8 bfr[2];
    #pragma unroll
    for (int nt = 0; nt < 2; ++nt) {
      int n = nt * 16 + l15;
      int cbs = (kc * 4 + lg) ^ (n & 7);
      bfr[nt] = *(const bf16x8*)&Xs[n][cbs * 8];
    }
    #pragma unroll
    for (int p = 0; p < 3; ++p) {
      #pragma unroll
      for (int ot = 0; ot < 2; ++ot) {
        const float* wr = Wp[p] + (size_t)(arow + ot * 16) * C_ + kc * 32 + kbase;
        f32x4 lo = *(const f32x4*)wr;
        f32x4 hi = *(const f32x4*)(wr + 4);
        bf16x8 af;
        if (p == 0) {
          #pragma unroll
          for (int i = 0; i < 4; ++i) {
            af[i]     = (bf16)(lo[i] * LOG2E_);
            af[4 + i] = (bf16)(hi[i] * LOG2E_);
          }
        } else {
          #pragma unroll
          for (int i = 0; i < 4; ++i) { af[i] = (bf16)lo[i]; af[4 + i] = (bf16)hi[i]; }
        }
        #pragma unroll
        for (int nt = 0; nt < 2; ++nt)
          acc[p][ot][nt] = mfma16(af, bfr[nt], acc[p][ot][nt]);
      }
    }
  }

  // ---- theta (p=0, log2e-scaled), phi (p=1): [b][n/32][ks 8][64][8]
  const float* Bp[3] = {b0, b1, b2};
  bf16* Op2[2] = {o0, o1};
  const int qtile = n0 >> 5;
  #pragma unroll
  for (int p = 0; p < 2; ++p) {
    bf16* dst = Op2[p] + (size_t)b * 128 * 8 * 512;
    #pragma unroll
    for (int ot = 0; ot < 2; ++ot) {
      int ks = w * 2 + ot;            // c>>4 (c = w*32+ot*16+lg*4+j)
      float bv[4];
      #pragma unroll
      for (int j = 0; j < 4; ++j) {
        float t = Bp[p][w * 32 + ot * 16 + lg * 4 + j];
        bv[j] = (p == 0) ? t * LOG2E_ : t;
      }
      #pragma unroll
      for (int nt = 0; nt < 2; ++nt) {
        int lanep = (nt * 16 + l15) + 32 * (lg >> 1);
        int elemb = (lg & 1) * 4;
        bf16x4 ov;
        #pragma unroll
        for (int j = 0; j < 4; ++j) ov[j] = (bf16)(acc[p][ot][nt][j] + bv[j]);
        *(bf16x4*)(dst + ((size_t)(qtile * 8 + ks) * 64 + lanep) * 8 + elemb) = ov;
      }
    }
  }
  // ---- g (p=2): [b][n/32 chunk][dtile 4][ks2 2][64][8]  (8KB per chunk)
  {
    bf16* dst = o2 + (size_t)b * 128 * 4096;
    const int t32 = n0 >> 5;
    #pragma unroll
    for (int ot = 0; ot < 2; ++ot) {
      #pragma unroll
      for (int j = 0; j < 4; ++j) {
        float bv = b2[w * 32 + ot * 16 + lg * 4 + j];
        int d31 = ot * 16 + lg * 4 + j;        // d&31 (dtile = w)
        #pragma unroll
        for (int nt = 0; nt < 2; ++nt) {       // nt = 16-row k-slice (ks2)
          int lanep = d31 + 32 * (l15 >> 3);
          dst[((size_t)((t32 * 4 + w) * 2 + nt) * 64 + lanep) * 8 + (l15 & 7)] =
              (bf16)(acc[2][ot][nt][j] + bv);
        }
      }
    }
  }
}

// ---------------------------------------------------------------------------
// Kernel 2: flash attention -- EXACT round-0 proven structure (48.2 us):
// 256 thr (4 waves), wave = 32 q-rows, 64-row KV tiles, K+V dbuf 64KB LDS
// via global_load_lds, one barrier/tile, dual-chain QK (s0,s1), exp1
// overlaps PV0 MFMAs, l on the matrix pipe via ones-A-frag MFMA.
// Only V frag-slot indexing adapted to the 32-row-chunk g layout
// (validated numerically in round 5).
// ---------------------------------------------------------------------------
__global__ __launch_bounds__(256, 2) void attn_kernel(
    const bf16* __restrict__ qf_, const bf16* __restrict__ kf_,
    const bf16* __restrict__ vf_,
    bf16* __restrict__ Opar, float* __restrict__ lpar)
{
  __shared__ bf16 Kb[2][8192];   // [chunk 2][ks 8][64][8] per 64-row tile
  __shared__ bf16 Vb[2][8192];   // [chunk 2][dtile 4][ks2 2][64][8]

  const int tid  = threadIdx.x;
  const int lane = tid & 63;
  const int w    = tid >> 6;
  const int l31  = lane & 31;
  const int b    = blockIdx.y;
  const int seg  = blockIdx.z;
  const int q0w  = blockIdx.x * 128 + w * 32;

  // Q fragments (B operand of S^T = K Q^T): 8 coalesced 1KB loads
  bf16x8 qf[8];
  {
    const bf16* qb = qf_ + ((size_t)(b * 128 + (q0w >> 5)) * 8) * 512 + lane * 8;
    #pragma unroll
    for (int ks = 0; ks < 8; ++ks)
      qf[ks] = *(const bf16x8*)(qb + ks * 512);
  }

  const bf16* ks_p = kf_ + (size_t)b * 128 * 4096 + (size_t)(seg * TPS_) * 8192 + tid * 8;
  const bf16* vs_p = vf_ + (size_t)b * 128 * 4096 + (size_t)(seg * TPS_) * 8192 + tid * 8;

  // prologue: stage tile 0 into buffer 0
  #pragma unroll
  for (int p = 0; p < 4; ++p) {
    gld_lds16(ks_p + p * 2048, &Kb[0][p * 2048 + tid * 8]);
    gld_lds16(vs_p + p * 2048, &Vb[0][p * 2048 + tid * 8]);
  }
  __syncthreads();

  f32x16 o_acc[4];
  #pragma unroll
  for (int dt = 0; dt < 4; ++dt)
    #pragma unroll
    for (int r = 0; r < 16; ++r) o_acc[dt][r] = 0.f;
  f32x16 lacc;
  #pragma unroll
  for (int r = 0; r < 16; ++r) lacc[r] = 0.f;

  const u32x4 onesu = {0x3F803F80u, 0x3F803F80u, 0x3F803F80u, 0x3F803F80u};
  const bf16x8 onesf = __builtin_bit_cast(bf16x8, onesu);

  for (int t = 0; t < TPS_; ++t) {
    const int cur = t & 1;
    // ---- issue next tile's DMA (overlaps with this tile's compute)
    if (t + 1 < TPS_) {
      const bf16* ksn = ks_p + (size_t)(t + 1) * 8192;
      const bf16* vsn = vs_p + (size_t)(t + 1) * 8192;
      #pragma unroll
      for (int p = 0; p < 4; ++p) {
        gld_lds16(ksn + p * 2048, &Kb[cur ^ 1][p * 2048 + tid * 8]);
        gld_lds16(vsn + p * 2048, &Vb[cur ^ 1][p * 2048 + tid * 8]);
      }
    }
    const bf16* Kc = Kb[cur];
    const bf16* Vc = Vb[cur];

    // ---- S^T = K Q^T (exp2 domain), both 32-row halves (2 indep chains)
    f32x16 s0, s1;
    #pragma unroll
    for (int r = 0; r < 16; ++r) { s0[r] = 0.f; s1[r] = 0.f; }
    __builtin_amdgcn_s_setprio(1);
    #pragma unroll
    for (int ks = 0; ks < 8; ++ks) {
      bf16x8 k0 = *(const bf16x8*)&Kc[((0 * 8 + ks) * 64 + lane) * 8];
      bf16x8 k1 = *(const bf16x8*)&Kc[((1 * 8 + ks) * 64 + lane) * 8];
      s0 = mfma32(k0, qf[ks], s0);
      s1 = mfma32(k1, qf[ks], s1);
    }
    __builtin_amdgcn_s_setprio(0);

    // ---- half 0: p = exp2(S' - SHIFT2); pack + permlane32_swap -> pf0, pf1
    bf16x8 pf0, pf1;
    exp_pack(s0, pf0, pf1);

    // ---- PV half 0 (+ l column-sum on matrix pipe)
    __builtin_amdgcn_s_setprio(1);
    #pragma unroll
    for (int dt = 0; dt < 4; ++dt) {
      bf16x8 vf = *(const bf16x8*)&Vc[((dt * 2 + 0) * 64 + lane) * 8];
      o_acc[dt] = mfma32(vf, pf0, o_acc[dt]);
    }
    lacc = mfma32(onesf, pf0, lacc);
    #pragma unroll
    for (int dt = 0; dt < 4; ++dt) {
      bf16x8 vf = *(const bf16x8*)&Vc[((dt * 2 + 1) * 64 + lane) * 8];
      o_acc[dt] = mfma32(vf, pf1, o_acc[dt]);
    }
    lacc = mfma32(onesf, pf1, lacc);
    __builtin_amdgcn_s_setprio(0);

    // ---- half 1 exp/pack (VALU; overlaps PV0 MFMAs across/within waves)
    bf16x8 pf2, pf3;
    exp_pack(s1, pf2, pf3);

    __builtin_amdgcn_s_setprio(1);
    #pragma unroll
    for (int dt = 0; dt < 4; ++dt) {
      bf16x8 vf = *(const bf16x8*)&Vc[4096 + ((dt * 2 + 0) * 64 + lane) * 8];
      o_acc[dt] = mfma32(vf, pf2, o_acc[dt]);
    }
    lacc = mfma32(onesf, pf2, lacc);
    #pragma unroll
    for (int dt = 0; dt < 4; ++dt) {
      bf16x8 vf = *(const bf16x8*)&Vc[4096 + ((dt * 2 + 1) * 64 + lane) * 8];
      o_acc[dt] = mfma32(vf, pf3, o_acc[dt]);
    }
    lacc = mfma32(onesf, pf3, lacc);
    __builtin_amdgcn_s_setprio(0);

    // one barrier per tile: drains next-tile DMA, protects buffers
    __syncthreads();
  }

  // ---- l: all 16 lacc rows identical = sum over this segment; col q = l31
  if (lane < 32)
    lpar[((size_t)seg * B_ + b) * N_ + q0w + lane] = lacc[0];

  // ---- store O^T partials (bf16): col=q=l31, row d = dt*32+R*8+4*(lane>>5)+i
  const int hh = lane >> 5;
  bf16* op = Opar + (((size_t)seg * B_ + b) * N_ + q0w + l31) * C2_;
  #pragma unroll
  for (int dt = 0; dt < 4; ++dt) {
    #pragma unroll
    for (int R = 0; R < 4; ++R) {
      bf16x4 v;
      #pragma unroll
      for (int i = 0; i < 4; ++i) v[i] = (bf16)o_acc[dt][4 * R + i];
      *(bf16x4*)(op + dt * 32 + R * 8 + hh * 4) = v;
    }
  }
}

// ---------------------------------------------------------------------------
// Kernel 3: fused combine + final conv + residual, 32-row n-tiles
// (512 blocks -> 2+ blocks/CU for the memory-bound combine phase).
// ---------------------------------------------------------------------------
__global__ __launch_bounds__(256) void final_kernel(
    const float* __restrict__ x, const float* __restrict__ wf,
    const float* __restrict__ bf_,
    const bf16* __restrict__ Opar, const float* __restrict__ lpar,
    float* __restrict__ out)
{
  __shared__ bf16 Ys[32][C2_ + 8];
  __shared__ float Linv[32];

  const int tid  = threadIdx.x;
  const int lane = tid & 63;
  const int w    = tid >> 6;
  const int n0   = blockIdx.x * 32;
  const int b    = blockIdx.y;
  const int l15  = lane & 15;
  const int lg   = lane >> 4;
  const int kbase = lg * 8;

  // ---- 1/l per row
  if (tid < 32) {
    float l = 0.f;
    #pragma unroll
    for (int s = 0; s < SEG_; ++s)
      l += lpar[((size_t)s * B_ + b) * N_ + n0 + tid];
    Linv[tid] = 1.f / l;
  }
  __syncthreads();

  // ---- stage y tile (sum bf16 segs in f32, normalize, repack bf16)
  #pragma unroll
  for (int it = 0; it < 2; ++it) {
    int idx = it * 256 + tid;          // 0..511 chunks of 8
    int r   = idx >> 4;
    int c8  = (idx & 15) * 8;
    float a[8] = {0.f, 0.f, 0.f, 0.f, 0.f, 0.f, 0.f, 0.f};
    #pragma unroll
    for (int s = 0; s < SEG_; ++s) {
      bf16x8 v = *(const bf16x8*)(Opar
          + (((size_t)s * B_ + b) * N_ + n0 + r) * C2_ + c8);
      #pragma unroll
      for (int j = 0; j < 8; ++j) a[j] += (float)v[j];
    }
    float inv = Linv[r];
    bf16x8 y;
    #pragma unroll
    for (int j = 0; j < 8; ++j) y[j] = (bf16)(a[j] * inv);
    *(bf16x8*)&Ys[r][c8] = y;
  }
  __syncthreads();

  // ---- GEMM: wave w owns c-rows [64w, 64w+64)
  const f32x4 fzero = {0.f, 0.f, 0.f, 0.f};
  f32x4 acc[4][2];
  #pragma unroll
  for (int rt = 0; rt < 4; ++rt)
    #pragma unroll
    for (int ct = 0; ct < 2; ++ct) acc[rt][ct] = fzero;

  for (int kc = 0; kc < 4; ++kc) {
    bf16x8 bfr[2];
    #pragma unroll
    for (int ct = 0; ct < 2; ++ct)
      bfr[ct] = *(const bf16x8*)&Ys[ct * 16 + l15][kc * 32 + kbase];
    #pragma unroll
    for (int rt = 0; rt < 4; ++rt) {
      const float* wr = wf + (size_t)(w * 64 + rt * 16 + l15) * C2_ + kc * 32 + kbase;
      f32x4 lo = *(const f32x4*)wr;
      f32x4 hi = *(const f32x4*)(wr + 4);
      bf16x8 af;
      #pragma unroll
      for (int i = 0; i < 4; ++i) { af[i] = (bf16)lo[i]; af[4 + i] = (bf16)hi[i]; }
      #pragma unroll
      for (int ct = 0; ct < 2; ++ct)
        acc[rt][ct] = mfma16(af, bfr[ct], acc[rt][ct]);
    }
  }

  #pragma unroll
  for (int rt = 0; rt < 4; ++rt) {
    int cbase = w * 64 + rt * 16 + lg * 4;
    #pragma unroll
    for (int j = 0; j < 4; ++j) {
      float bias = bf_[cbase + j];
      #pragma unroll
      for (int ct = 0; ct < 2; ++ct) {
        int n = n0 + ct * 16 + l15;
        size_t idx = ((size_t)b * C_ + cbase + j) * N_ + n;
        out[idx] = x[idx] + bias + acc[rt][ct][j];
      }
    }
  }
}

// ---------------------------------------------------------------------------
extern "C" void kernel_launch(void* const* d_in, const int* in_sizes, int n_in,
                              void* d_out, int out_size, void* d_ws, size_t ws_size,
                              hipStream_t stream) {
  const float* x       = (const float*)d_in[0];
  const float* w_theta = (const float*)d_in[1];
  const float* b_theta = (const float*)d_in[2];
  const float* w_phi   = (const float*)d_in[3];
  const float* b_phi   = (const float*)d_in[4];
  const float* w_g     = (const float*)d_in[5];
  const float* b_g     = (const float*)d_in[6];
  const float* w_final = (const float*)d_in[7];
  const float* b_final = (const float*)d_in[8];
  float* out = (float*)d_out;

  char* ws = (char*)d_ws;
  const size_t SZB = (size_t)B_ * N_ * C2_ * sizeof(bf16);   // 4 MB each
  bf16*  th = (bf16*)(ws);
  bf16*  ph = (bf16*)(ws + SZB);
  bf16*  gt = (bf16*)(ws + 2 * SZB);
  bf16*  OparB = (bf16*)(ws + 3 * SZB);                      // SEG_ x 4 MB (bf16)
  float* lpar  = (float*)(ws + 3 * SZB + SEG_ * SZB);        // 256 KB

  proj_kernel<<<dim3(N_ / 32, B_), 256, 0, stream>>>(
      x, w_theta, b_theta, w_phi, b_phi, w_g, b_g, th, ph, gt);
  attn_kernel<<<dim3(N_ / 128, B_, SEG_), 256, 0, stream>>>(
      th, ph, gt, OparB, lpar);
  final_kernel<<<dim3(N_ / 32, B_), 256, 0, stream>>>(
      x, w_final, b_final, OparB, lpar, out);
}

// Round 7
// 77.445 us; speedup vs baseline: 1.1988x; 1.1988x over previous
//
#include <hip/hip_runtime.h>

#define B_ 4
#define C_ 256
#define C2_ 128
#define N_ 4096
#define SEG_ 4
#define TPS_ (N_ / 64 / SEG_)   // 16 KV tiles (64 rows) per segment
#define LOG2E_ 1.4426950408889634f
#define SHIFT2_ 43.28085122666891f   // 30 * log2(e); softmax in exp2 domain

typedef __bf16 bf16;
typedef __bf16 bf16x8 __attribute__((ext_vector_type(8)));
typedef __bf16 bf16x4 __attribute__((ext_vector_type(4)));
typedef __bf16 bf16x2 __attribute__((ext_vector_type(2)));
typedef float f32x4 __attribute__((ext_vector_type(4)));
typedef float f32x16 __attribute__((ext_vector_type(16)));
typedef unsigned int u32x4 __attribute__((ext_vector_type(4)));

__device__ __forceinline__ f32x4 mfma16(bf16x8 a, bf16x8 b, f32x4 c) {
  return __builtin_amdgcn_mfma_f32_16x16x32_bf16(a, b, c, 0, 0, 0);
}
__device__ __forceinline__ f32x16 mfma32(bf16x8 a, bf16x8 b, f32x16 c) {
  return __builtin_amdgcn_mfma_f32_32x32x16_bf16(a, b, c, 0, 0, 0);
}

__device__ __forceinline__ float fexp2(float x) {
#if __has_builtin(__builtin_amdgcn_exp2f)
  return __builtin_amdgcn_exp2f(x);
#else
  return exp2f(x);
#endif
}

// async global->LDS, 16B per lane (dest = wave-uniform base + lane*16)
typedef const __attribute__((address_space(1))) uint32_t* gas_ptr;
typedef __attribute__((address_space(3))) uint32_t* las_ptr;
__device__ __forceinline__ void gld_lds16(const bf16* g, bf16* l) {
  __builtin_amdgcn_global_load_lds((gas_ptr)g, (las_ptr)l, 16, 0, 0);
}

// pack two f32 -> one dword of 2 bf16
__device__ __forceinline__ uint32_t pk2(float a, float b) {
  bf16x2 v; v[0] = (bf16)a; v[1] = (bf16)b;
  return __builtin_bit_cast(uint32_t, v);
}
// v_permlane32_swap_b32: a[l>=32] <-> b[l<32]  (VALU cross-lane, no LDS pipe)
__device__ __forceinline__ void pl32swap(uint32_t& a, uint32_t& b) {
  asm volatile("v_permlane32_swap_b32 %0, %1" : "+v"(a), "+v"(b));
}

// exp2-domain softmax numerator + bf16 pack/transpose (l done via ones-MFMA)
__device__ __forceinline__ void exp_pack(const f32x16& s,
                                         bf16x8& pf0, bf16x8& pf1) {
  float p[16];
  #pragma unroll
  for (int r = 0; r < 16; ++r) p[r] = fexp2(s[r] - SHIFT2_);
  uint32_t A[4], Bb[4];
  #pragma unroll
  for (int G = 0; G < 4; ++G) {
    A[G]  = pk2(p[4 * G + 0], p[4 * G + 1]);
    Bb[G] = pk2(p[4 * G + 2], p[4 * G + 3]);
  }
  pl32swap(A[0], A[1]);  pl32swap(Bb[0], Bb[1]);
  { u32x4 dv = {A[0], Bb[0], A[1], Bb[1]}; pf0 = __builtin_bit_cast(bf16x8, dv); }
  pl32swap(A[2], A[3]);  pl32swap(Bb[2], Bb[3]);
  { u32x4 dv = {A[2], Bb[2], A[3], Bb[3]}; pf1 = __builtin_bit_cast(bf16x8, dv); }
}

// 32x32x16 fragment layouts:
//  A/B: lane = idx%32 + 32*((k%16)/8), elem = k%8 (8 bf16 / 4 VGPRs)
//  C/D: col = lane&31, row = (reg&3) + 8*(reg>>2) + 4*(lane>>5)
// Operand storage (fragment-major, wave reads = linear 1KB):
//  theta/phi: [b][n/32][ks 8][64][8]   (theta pre-scaled by log2e)
//  g (V^T):   [b][n/32 chunk][dtile 4][ks2 2][64][8] (8KB per 32-row chunk)

// ---------------------------------------------------------------------------
// Kernel 1: fused 3-way 1x1-conv projections. 64-row n-tiles (proven
// coalescing + W amortization), but 512 threads / 8 waves per block:
// 2 waves/SIMD for latency hiding (was 1). Wave w owns 48 of the 384
// concatenated output rows (3 x 16-row MFMA blocks); matrix p = row>>7
// is wave-uniform.
// ---------------------------------------------------------------------------
__global__ __launch_bounds__(512, 2) void proj_kernel(
    const float* __restrict__ x,
    const float* __restrict__ w0, const float* __restrict__ b0,
    const float* __restrict__ w1, const float* __restrict__ b1,
    const float* __restrict__ w2, const float* __restrict__ b2,
    bf16* __restrict__ o0, bf16* __restrict__ o1, bf16* __restrict__ o2)
{
  __shared__ bf16 Xs[64][C_];   // [n][c], 16B block cb swizzled: cb ^= (n&7)
  const int tid  = threadIdx.x;
  const int lane = tid & 63;
  const int w    = tid >> 6;       // 0..7
  const int n0   = blockIdx.x * 64;
  const int b    = blockIdx.y;
  const int l15  = lane & 15;
  const int lg   = lane >> 4;
  const float* xb = x + (size_t)b * C_ * N_;

  // stage X^T: thread owns row n=lane, wave w covers c in [32w, 32w+32)
  {
    const int nl = lane;
    #pragma unroll
    for (int g = 0; g < 4; ++g) {
      int c0 = w * 32 + g * 8;
      bf16x8 h;
      #pragma unroll
      for (int i = 0; i < 8; ++i)
        h[i] = (bf16)xb[(size_t)(c0 + i) * N_ + n0 + nl];
      int cbs = (c0 >> 3) ^ (nl & 7);
      *(bf16x8*)&Xs[nl][cbs * 8] = h;
    }
  }
  __syncthreads();

  const f32x4 fzero = {0.f, 0.f, 0.f, 0.f};
  f32x4 acc[3][4];                 // [ot 3][nt 4]
  #pragma unroll
  for (int ot = 0; ot < 3; ++ot)
    #pragma unroll
    for (int nt = 0; nt < 4; ++nt) acc[ot][nt] = fzero;

  const float* Wp[3] = {w0, w1, w2};
  const int kbase = lg * 8;

  for (int kc = 0; kc < 8; ++kc) {
    bf16x8 bfr[4];
    #pragma unroll
    for (int nt = 0; nt < 4; ++nt) {
      int n = nt * 16 + l15;
      int cbs = (kc * 4 + lg) ^ (n & 7);
      bfr[nt] = *(const bf16x8*)&Xs[n][cbs * 8];
    }
    #pragma unroll
    for (int ot = 0; ot < 3; ++ot) {
      int r0 = w * 48 + ot * 16;          // concatenated output row base
      int p  = r0 >> 7;                   // matrix (wave-uniform)
      int rr = r0 & 127;                  // row within matrix
      const float* wr = Wp[p] + (size_t)(rr + l15) * C_ + kc * 32 + kbase;
      f32x4 lo = *(const f32x4*)wr;
      f32x4 hi = *(const f32x4*)(wr + 4);
      bf16x8 af;
      if (p == 0) {
        #pragma unroll
        for (int i = 0; i < 4; ++i) {
          af[i]     = (bf16)(lo[i] * LOG2E_);
          af[4 + i] = (bf16)(hi[i] * LOG2E_);
        }
      } else {
        #pragma unroll
        for (int i = 0; i < 4; ++i) { af[i] = (bf16)lo[i]; af[4 + i] = (bf16)hi[i]; }
      }
      #pragma unroll
      for (int nt = 0; nt < 4; ++nt)
        acc[ot][nt] = mfma16(af, bfr[nt], acc[ot][nt]);
    }
  }

  // ---- writers: per ot, matrix p = (w*48+ot*16)>>7 (wave-uniform)
  const float* Bp[3] = {b0, b1, b2};
  bf16* Op2[2] = {o0, o1};
  #pragma unroll
  for (int ot = 0; ot < 3; ++ot) {
    int r0 = w * 48 + ot * 16;
    int p  = r0 >> 7;
    int rr = r0 & 127;
    if (p < 2) {
      // theta/phi: [b][n/32][ks 8][64][8]
      bf16* dst = Op2[p] + (size_t)b * 128 * 8 * 512;
      int ks = rr >> 4;
      float bv[4];
      #pragma unroll
      for (int j = 0; j < 4; ++j) {
        float t = Bp[p][rr + lg * 4 + j];
        bv[j] = (p == 0) ? t * LOG2E_ : t;
      }
      #pragma unroll
      for (int nt = 0; nt < 4; ++nt) {
        int qtile = (n0 >> 5) + (nt >> 1);
        int lanep = ((nt & 1) * 16 + l15) + 32 * (lg >> 1);
        int elemb = (lg & 1) * 4;
        bf16x4 ov;
        #pragma unroll
        for (int j = 0; j < 4; ++j) ov[j] = (bf16)(acc[ot][nt][j] + bv[j]);
        *(bf16x4*)(dst + ((size_t)(qtile * 8 + ks) * 64 + lanep) * 8 + elemb) = ov;
      }
    } else {
      // g: [b][n/32 chunk][dtile 4][ks2 2][64][8]
      bf16* dst = o2 + (size_t)b * 128 * 4096;
      const int t32b = n0 >> 5;
      int dtile = rr >> 5;
      #pragma unroll
      for (int j = 0; j < 4; ++j) {
        float bv = b2[rr + lg * 4 + j];
        int d31 = (rr & 31) + lg * 4 + j;
        #pragma unroll
        for (int nt = 0; nt < 4; ++nt) {
          int t32 = t32b + (nt >> 1);
          int ks2 = nt & 1;
          int lanep = d31 + 32 * (l15 >> 3);
          dst[((size_t)((t32 * 4 + dtile) * 2 + ks2) * 64 + lanep) * 8 + (l15 & 7)] =
              (bf16)(acc[ot][nt][j] + bv);
        }
      }
    }
  }
}

// ---------------------------------------------------------------------------
// Kernel 2: flash attention -- round-0/6 proven structure, UNCHANGED
// (measured 47.5-48.2 us, VGPR 104, verified).
// ---------------------------------------------------------------------------
__global__ __launch_bounds__(256, 2) void attn_kernel(
    const bf16* __restrict__ qf_, const bf16* __restrict__ kf_,
    const bf16* __restrict__ vf_,
    bf16* __restrict__ Opar, float* __restrict__ lpar)
{
  __shared__ bf16 Kb[2][8192];   // [chunk 2][ks 8][64][8] per 64-row tile
  __shared__ bf16 Vb[2][8192];   // [chunk 2][dtile 4][ks2 2][64][8]

  const int tid  = threadIdx.x;
  const int lane = tid & 63;
  const int w    = tid >> 6;
  const int l31  = lane & 31;
  const int b    = blockIdx.y;
  const int seg  = blockIdx.z;
  const int q0w  = blockIdx.x * 128 + w * 32;

  // Q fragments (B operand of S^T = K Q^T): 8 coalesced 1KB loads
  bf16x8 qf[8];
  {
    const bf16* qb = qf_ + ((size_t)(b * 128 + (q0w >> 5)) * 8) * 512 + lane * 8;
    #pragma unroll
    for (int ks = 0; ks < 8; ++ks)
      qf[ks] = *(const bf16x8*)(qb + ks * 512);
  }

  const bf16* ks_p = kf_ + (size_t)b * 128 * 4096 + (size_t)(seg * TPS_) * 8192 + tid * 8;
  const bf16* vs_p = vf_ + (size_t)b * 128 * 4096 + (size_t)(seg * TPS_) * 8192 + tid * 8;

  // prologue: stage tile 0 into buffer 0
  #pragma unroll
  for (int p = 0; p < 4; ++p) {
    gld_lds16(ks_p + p * 2048, &Kb[0][p * 2048 + tid * 8]);
    gld_lds16(vs_p + p * 2048, &Vb[0][p * 2048 + tid * 8]);
  }
  __syncthreads();

  f32x16 o_acc[4];
  #pragma unroll
  for (int dt = 0; dt < 4; ++dt)
    #pragma unroll
    for (int r = 0; r < 16; ++r) o_acc[dt][r] = 0.f;
  f32x16 lacc;
  #pragma unroll
  for (int r = 0; r < 16; ++r) lacc[r] = 0.f;

  const u32x4 onesu = {0x3F803F80u, 0x3F803F80u, 0x3F803F80u, 0x3F803F80u};
  const bf16x8 onesf = __builtin_bit_cast(bf16x8, onesu);

  for (int t = 0; t < TPS_; ++t) {
    const int cur = t & 1;
    // ---- issue next tile's DMA (overlaps with this tile's compute)
    if (t + 1 < TPS_) {
      const bf16* ksn = ks_p + (size_t)(t + 1) * 8192;
      const bf16* vsn = vs_p + (size_t)(t + 1) * 8192;
      #pragma unroll
      for (int p = 0; p < 4; ++p) {
        gld_lds16(ksn + p * 2048, &Kb[cur ^ 1][p * 2048 + tid * 8]);
        gld_lds16(vsn + p * 2048, &Vb[cur ^ 1][p * 2048 + tid * 8]);
      }
    }
    const bf16* Kc = Kb[cur];
    const bf16* Vc = Vb[cur];

    // ---- S^T = K Q^T (exp2 domain), both 32-row halves (2 indep chains)
    f32x16 s0, s1;
    #pragma unroll
    for (int r = 0; r < 16; ++r) { s0[r] = 0.f; s1[r] = 0.f; }
    __builtin_amdgcn_s_setprio(1);
    #pragma unroll
    for (int ks = 0; ks < 8; ++ks) {
      bf16x8 k0 = *(const bf16x8*)&Kc[((0 * 8 + ks) * 64 + lane) * 8];
      bf16x8 k1 = *(const bf16x8*)&Kc[((1 * 8 + ks) * 64 + lane) * 8];
      s0 = mfma32(k0, qf[ks], s0);
      s1 = mfma32(k1, qf[ks], s1);
    }
    __builtin_amdgcn_s_setprio(0);

    // ---- half 0: p = exp2(S' - SHIFT2); pack + permlane32_swap -> pf0, pf1
    bf16x8 pf0, pf1;
    exp_pack(s0, pf0, pf1);

    // ---- PV half 0 (+ l column-sum on matrix pipe)
    __builtin_amdgcn_s_setprio(1);
    #pragma unroll
    for (int dt = 0; dt < 4; ++dt) {
      bf16x8 vf = *(const bf16x8*)&Vc[((dt * 2 + 0) * 64 + lane) * 8];
      o_acc[dt] = mfma32(vf, pf0, o_acc[dt]);
    }
    lacc = mfma32(onesf, pf0, lacc);
    #pragma unroll
    for (int dt = 0; dt < 4; ++dt) {
      bf16x8 vf = *(const bf16x8*)&Vc[((dt * 2 + 1) * 64 + lane) * 8];
      o_acc[dt] = mfma32(vf, pf1, o_acc[dt]);
    }
    lacc = mfma32(onesf, pf1, lacc);
    __builtin_amdgcn_s_setprio(0);

    // ---- half 1 exp/pack (VALU; overlaps PV0 MFMAs across/within waves)
    bf16x8 pf2, pf3;
    exp_pack(s1, pf2, pf3);

    __builtin_amdgcn_s_setprio(1);
    #pragma unroll
    for (int dt = 0; dt < 4; ++dt) {
      bf16x8 vf = *(const bf16x8*)&Vc[4096 + ((dt * 2 + 0) * 64 + lane) * 8];
      o_acc[dt] = mfma32(vf, pf2, o_acc[dt]);
    }
    lacc = mfma32(onesf, pf2, lacc);
    #pragma unroll
    for (int dt = 0; dt < 4; ++dt) {
      bf16x8 vf = *(const bf16x8*)&Vc[4096 + ((dt * 2 + 1) * 64 + lane) * 8];
      o_acc[dt] = mfma32(vf, pf3, o_acc[dt]);
    }
    lacc = mfma32(onesf, pf3, lacc);
    __builtin_amdgcn_s_setprio(0);

    // one barrier per tile: drains next-tile DMA, protects buffers
    __syncthreads();
  }

  // ---- l: all 16 lacc rows identical = sum over this segment; col q = l31
  if (lane < 32)
    lpar[((size_t)seg * B_ + b) * N_ + q0w + lane] = lacc[0];

  // ---- store O^T partials (bf16): col=q=l31, row d = dt*32+R*8+4*(lane>>5)+i
  const int hh = lane >> 5;
  bf16* op = Opar + (((size_t)seg * B_ + b) * N_ + q0w + l31) * C2_;
  #pragma unroll
  for (int dt = 0; dt < 4; ++dt) {
    #pragma unroll
    for (int R = 0; R < 4; ++R) {
      bf16x4 v;
      #pragma unroll
      for (int i = 0; i < 4; ++i) v[i] = (bf16)o_acc[dt][4 * R + i];
      *(bf16x4*)(op + dt * 32 + R * 8 + hh * 4) = v;
    }
  }
}

// ---------------------------------------------------------------------------
// Kernel 3: fused combine + final conv + residual. 64-row n-tiles, 512
// threads / 8 waves (2 waves/SIMD): wave w owns 32 of the 256 c-rows.
// ---------------------------------------------------------------------------
__global__ __launch_bounds__(512, 2) void final_kernel(
    const float* __restrict__ x, const float* __restrict__ wf,
    const float* __restrict__ bf_,
    const bf16* __restrict__ Opar, const float* __restrict__ lpar,
    float* __restrict__ out)
{
  __shared__ bf16 Ys[64][C2_ + 8];
  __shared__ float Linv[64];

  const int tid  = threadIdx.x;
  const int lane = tid & 63;
  const int w    = tid >> 6;       // 0..7
  const int n0   = blockIdx.x * 64;
  const int b    = blockIdx.y;
  const int l15  = lane & 15;
  const int lg   = lane >> 4;
  const int kbase = lg * 8;

  // ---- 1/l per row
  if (tid < 64) {
    float l = 0.f;
    #pragma unroll
    for (int s = 0; s < SEG_; ++s)
      l += lpar[((size_t)s * B_ + b) * N_ + n0 + tid];
    Linv[tid] = 1.f / l;
  }
  __syncthreads();

  // ---- stage y tile (sum bf16 segs in f32, normalize, repack bf16)
  #pragma unroll
  for (int it = 0; it < 2; ++it) {
    int idx = it * 512 + tid;          // 0..1023 chunks of 8
    int r   = idx >> 4;
    int c8  = (idx & 15) * 8;
    float a[8] = {0.f, 0.f, 0.f, 0.f, 0.f, 0.f, 0.f, 0.f};
    #pragma unroll
    for (int s = 0; s < SEG_; ++s) {
      bf16x8 v = *(const bf16x8*)(Opar
          + (((size_t)s * B_ + b) * N_ + n0 + r) * C2_ + c8);
      #pragma unroll
      for (int j = 0; j < 8; ++j) a[j] += (float)v[j];
    }
    float inv = Linv[r];
    bf16x8 y;
    #pragma unroll
    for (int j = 0; j < 8; ++j) y[j] = (bf16)(a[j] * inv);
    *(bf16x8*)&Ys[r][c8] = y;
  }
  __syncthreads();

  // ---- GEMM: wave w owns c-rows [32w, 32w+32)
  const f32x4 fzero = {0.f, 0.f, 0.f, 0.f};
  f32x4 acc[2][4];
  #pragma unroll
  for (int rt = 0; rt < 2; ++rt)
    #pragma unroll
    for (int ct = 0; ct < 4; ++ct) acc[rt][ct] = fzero;

  for (int kc = 0; kc < 4; ++kc) {
    bf16x8 bfr[4];
    #pragma unroll
    for (int ct = 0; ct < 4; ++ct)
      bfr[ct] = *(const bf16x8*)&Ys[ct * 16 + l15][kc * 32 + kbase];
    #pragma unroll
    for (int rt = 0; rt < 2; ++rt) {
      const float* wr = wf + (size_t)(w * 32 + rt * 16 + l15) * C2_ + kc * 32 + kbase;
      f32x4 lo = *(const f32x4*)wr;
      f32x4 hi = *(const f32x4*)(wr + 4);
      bf16x8 af;
      #pragma unroll
      for (int i = 0; i < 4; ++i) { af[i] = (bf16)lo[i]; af[4 + i] = (bf16)hi[i]; }
      #pragma unroll
      for (int ct = 0; ct < 4; ++ct)
        acc[rt][ct] = mfma16(af, bfr[ct], acc[rt][ct]);
    }
  }

  #pragma unroll
  for (int rt = 0; rt < 2; ++rt) {
    int cbase = w * 32 + rt * 16 + lg * 4;
    #pragma unroll
    for (int j = 0; j < 4; ++j) {
      float bias = bf_[cbase + j];
      #pragma unroll
      for (int ct = 0; ct < 4; ++ct) {
        int n = n0 + ct * 16 + l15;
        size_t idx = ((size_t)b * C_ + cbase + j) * N_ + n;
        out[idx] = x[idx] + bias + acc[rt][ct][j];
      }
    }
  }
}

// ---------------------------------------------------------------------------
extern "C" void kernel_launch(void* const* d_in, const int* in_sizes, int n_in,
                              void* d_out, int out_size, void* d_ws, size_t ws_size,
                              hipStream_t stream) {
  const float* x       = (const float*)d_in[0];
  const float* w_theta = (const float*)d_in[1];
  const float* b_theta = (const float*)d_in[2];
  const float* w_phi   = (const float*)d_in[3];
  const float* b_phi   = (const float*)d_in[4];
  const float* w_g     = (const float*)d_in[5];
  const float* b_g     = (const float*)d_in[6];
  const float* w_final = (const float*)d_in[7];
  const float* b_final = (const float*)d_in[8];
  float* out = (float*)d_out;

  char* ws = (char*)d_ws;
  const size_t SZB = (size_t)B_ * N_ * C2_ * sizeof(bf16);   // 4 MB each
  bf16*  th = (bf16*)(ws);
  bf16*  ph = (bf16*)(ws + SZB);
  bf16*  gt = (bf16*)(ws + 2 * SZB);
  bf16*  OparB = (bf16*)(ws + 3 * SZB);                      // SEG_ x 4 MB (bf16)
  float* lpar  = (float*)(ws + 3 * SZB + SEG_ * SZB);        // 256 KB

  proj_kernel<<<dim3(N_ / 64, B_), 512, 0, stream>>>(
      x, w_theta, b_theta, w_phi, b_phi, w_g, b_g, th, ph, gt);
  attn_kernel<<<dim3(N_ / 128, B_, SEG_), 256, 0, stream>>>(
      th, ph, gt, OparB, lpar);
  final_kernel<<<dim3(N_ / 64, B_), 512, 0, stream>>>(
      x, w_final, b_final, OparB, lpar, out);
}

// Round 8
// 74.758 us; speedup vs baseline: 1.2419x; 1.0359x over previous
//
#include <hip/hip_runtime.h>

#define B_ 4
#define C_ 256
#define C2_ 128
#define N_ 4096
#define SEG_ 4
#define TPS_ (N_ / 64 / SEG_)   // 16 KV tiles (64 rows) per segment
#define LOG2E_ 1.4426950408889634f
#define SHIFT2_ 43.28085122666891f   // 30 * log2(e); softmax in exp2 domain

typedef __bf16 bf16;
typedef __bf16 bf16x8 __attribute__((ext_vector_type(8)));
typedef __bf16 bf16x4 __attribute__((ext_vector_type(4)));
typedef __bf16 bf16x2 __attribute__((ext_vector_type(2)));
typedef float f32x4 __attribute__((ext_vector_type(4)));
typedef float f32x16 __attribute__((ext_vector_type(16)));
typedef unsigned int u32x4 __attribute__((ext_vector_type(4)));

__device__ __forceinline__ f32x4 mfma16(bf16x8 a, bf16x8 b, f32x4 c) {
  return __builtin_amdgcn_mfma_f32_16x16x32_bf16(a, b, c, 0, 0, 0);
}
__device__ __forceinline__ f32x16 mfma32(bf16x8 a, bf16x8 b, f32x16 c) {
  return __builtin_amdgcn_mfma_f32_32x32x16_bf16(a, b, c, 0, 0, 0);
}

__device__ __forceinline__ float fexp2(float x) {
#if __has_builtin(__builtin_amdgcn_exp2f)
  return __builtin_amdgcn_exp2f(x);
#else
  return exp2f(x);
#endif
}

// async global->LDS, 16B per lane (dest = wave-uniform base + lane*16)
typedef const __attribute__((address_space(1))) uint32_t* gas_ptr;
typedef __attribute__((address_space(3))) uint32_t* las_ptr;
__device__ __forceinline__ void gld_lds16(const bf16* g, bf16* l) {
  __builtin_amdgcn_global_load_lds((gas_ptr)g, (las_ptr)l, 16, 0, 0);
}

// pack two f32 -> one dword of 2 bf16
__device__ __forceinline__ uint32_t pk2(float a, float b) {
  bf16x2 v; v[0] = (bf16)a; v[1] = (bf16)b;
  return __builtin_bit_cast(uint32_t, v);
}
// v_permlane32_swap_b32: a[l>=32] <-> b[l<32]  (VALU cross-lane, no LDS pipe)
__device__ __forceinline__ void pl32swap(uint32_t& a, uint32_t& b) {
  asm volatile("v_permlane32_swap_b32 %0, %1" : "+v"(a), "+v"(b));
}

// exp2-domain softmax numerator + bf16 pack/transpose (l done via ones-MFMA)
__device__ __forceinline__ void exp_pack(const f32x16& s,
                                         bf16x8& pf0, bf16x8& pf1) {
  float p[16];
  #pragma unroll
  for (int r = 0; r < 16; ++r) p[r] = fexp2(s[r] - SHIFT2_);
  uint32_t A[4], Bb[4];
  #pragma unroll
  for (int G = 0; G < 4; ++G) {
    A[G]  = pk2(p[4 * G + 0], p[4 * G + 1]);
    Bb[G] = pk2(p[4 * G + 2], p[4 * G + 3]);
  }
  pl32swap(A[0], A[1]);  pl32swap(Bb[0], Bb[1]);
  { u32x4 dv = {A[0], Bb[0], A[1], Bb[1]}; pf0 = __builtin_bit_cast(bf16x8, dv); }
  pl32swap(A[2], A[3]);  pl32swap(Bb[2], Bb[3]);
  { u32x4 dv = {A[2], Bb[2], A[3], Bb[3]}; pf1 = __builtin_bit_cast(bf16x8, dv); }
}

// 32x32x16 fragment layouts:
//  A/B: lane = idx%32 + 32*((k%16)/8), elem = k%8 (8 bf16 / 4 VGPRs)
//  C/D: col = lane&31, row = (reg&3) + 8*(reg>>2) + 4*(lane>>5)
// Operand storage (fragment-major, wave reads = linear 1KB):
//  theta/phi: [b][n/32][ks 8][64][8]   (theta pre-scaled by log2e)
//  g (V^T):   [b][n/32 chunk][dtile 4][ks2 2][64][8] (8KB per 32-row chunk)

// ---------------------------------------------------------------------------
// Kernel 1: fused 3-way 1x1-conv projections. 64-row n-tiles, 768 threads
// (12 waves = 3 waves/SIMD at 1 block/CU; was 2). Wave w (0..11) owns 32
// of the 384 concatenated output rows; matrix p = w>>2 is wave-uniform.
// Staging: linear chunk-task split (2048 tasks of 8 elems, wave-uniform
// guard), same swizzle/coalescing as before.
// ---------------------------------------------------------------------------
__global__ __launch_bounds__(768, 3) void proj_kernel(
    const float* __restrict__ x,
    const float* __restrict__ w0, const float* __restrict__ b0,
    const float* __restrict__ w1, const float* __restrict__ b1,
    const float* __restrict__ w2, const float* __restrict__ b2,
    bf16* __restrict__ o0, bf16* __restrict__ o1, bf16* __restrict__ o2)
{
  __shared__ bf16 Xs[64][C_];   // [n][c], 16B block cb swizzled: cb ^= (n&7)
  const int tid  = threadIdx.x;
  const int lane = tid & 63;
  const int w    = tid >> 6;       // 0..11
  const int n0   = blockIdx.x * 64;
  const int b    = blockIdx.y;
  const int l15  = lane & 15;
  const int lg   = lane >> 4;
  const float* xb = x + (size_t)b * C_ * N_;

  // stage X^T: task idx = cc*64 + n (cc = 8-c chunk); lanes -> consecutive n
  #pragma unroll
  for (int it = 0; it < 3; ++it) {
    int idx = it * 768 + tid;
    if (idx < 2048) {
      int n  = idx & 63;
      int cc = idx >> 6;
      bf16x8 h;
      #pragma unroll
      for (int i = 0; i < 8; ++i)
        h[i] = (bf16)xb[(size_t)(cc * 8 + i) * N_ + n0 + n];
      int cbs = cc ^ (n & 7);
      *(bf16x8*)&Xs[n][cbs * 8] = h;
    }
  }
  __syncthreads();

  const f32x4 fzero = {0.f, 0.f, 0.f, 0.f};
  f32x4 acc[2][4];                 // [ot 2][nt 4]
  #pragma unroll
  for (int ot = 0; ot < 2; ++ot)
    #pragma unroll
    for (int nt = 0; nt < 4; ++nt) acc[ot][nt] = fzero;

  const float* Wp[3] = {w0, w1, w2};
  const int kbase = lg * 8;
  const int p  = w >> 2;             // matrix (wave-uniform)
  const int rr0 = (w * 32) & 127;    // row base within matrix

  for (int kc = 0; kc < 8; ++kc) {
    bf16x8 bfr[4];
    #pragma unroll
    for (int nt = 0; nt < 4; ++nt) {
      int n = nt * 16 + l15;
      int cbs = (kc * 4 + lg) ^ (n & 7);
      bfr[nt] = *(const bf16x8*)&Xs[n][cbs * 8];
    }
    #pragma unroll
    for (int ot = 0; ot < 2; ++ot) {
      int rr = rr0 + ot * 16;
      const float* wr = Wp[p] + (size_t)(rr + l15) * C_ + kc * 32 + kbase;
      f32x4 lo = *(const f32x4*)wr;
      f32x4 hi = *(const f32x4*)(wr + 4);
      bf16x8 af;
      if (p == 0) {
        #pragma unroll
        for (int i = 0; i < 4; ++i) {
          af[i]     = (bf16)(lo[i] * LOG2E_);
          af[4 + i] = (bf16)(hi[i] * LOG2E_);
        }
      } else {
        #pragma unroll
        for (int i = 0; i < 4; ++i) { af[i] = (bf16)lo[i]; af[4 + i] = (bf16)hi[i]; }
      }
      #pragma unroll
      for (int nt = 0; nt < 4; ++nt)
        acc[ot][nt] = mfma16(af, bfr[nt], acc[ot][nt]);
    }
  }

  // ---- writers (matrix p wave-uniform)
  const float* Bp[3] = {b0, b1, b2};
  bf16* Op2[2] = {o0, o1};
  #pragma unroll
  for (int ot = 0; ot < 2; ++ot) {
    int rr = rr0 + ot * 16;
    if (p < 2) {
      // theta/phi: [b][n/32][ks 8][64][8]
      bf16* dst = Op2[p] + (size_t)b * 128 * 8 * 512;
      int ks = rr >> 4;
      float bv[4];
      #pragma unroll
      for (int j = 0; j < 4; ++j) {
        float t = Bp[p][rr + lg * 4 + j];
        bv[j] = (p == 0) ? t * LOG2E_ : t;
      }
      #pragma unroll
      for (int nt = 0; nt < 4; ++nt) {
        int qtile = (n0 >> 5) + (nt >> 1);
        int lanep = ((nt & 1) * 16 + l15) + 32 * (lg >> 1);
        int elemb = (lg & 1) * 4;
        bf16x4 ov;
        #pragma unroll
        for (int j = 0; j < 4; ++j) ov[j] = (bf16)(acc[ot][nt][j] + bv[j]);
        *(bf16x4*)(dst + ((size_t)(qtile * 8 + ks) * 64 + lanep) * 8 + elemb) = ov;
      }
    } else {
      // g: [b][n/32 chunk][dtile 4][ks2 2][64][8]
      bf16* dst = o2 + (size_t)b * 128 * 4096;
      const int t32b = n0 >> 5;
      int dtile = rr >> 5;
      #pragma unroll
      for (int j = 0; j < 4; ++j) {
        float bv = b2[rr + lg * 4 + j];
        int d31 = (rr & 31) + lg * 4 + j;
        #pragma unroll
        for (int nt = 0; nt < 4; ++nt) {
          int t32 = t32b + (nt >> 1);
          int ks2 = nt & 1;
          int lanep = d31 + 32 * (l15 >> 3);
          dst[((size_t)((t32 * 4 + dtile) * 2 + ks2) * 64 + lanep) * 8 + (l15 & 7)] =
              (bf16)(acc[ot][nt][j] + bv);
        }
      }
    }
  }
}

// ---------------------------------------------------------------------------
// Kernel 2: flash attention -- round-0/6/7 proven structure, UNCHANGED
// (measured 47.5-48.4 us across 3 rounds, VGPR 104).
// ---------------------------------------------------------------------------
__global__ __launch_bounds__(256, 2) void attn_kernel(
    const bf16* __restrict__ qf_, const bf16* __restrict__ kf_,
    const bf16* __restrict__ vf_,
    bf16* __restrict__ Opar, float* __restrict__ lpar)
{
  __shared__ bf16 Kb[2][8192];   // [chunk 2][ks 8][64][8] per 64-row tile
  __shared__ bf16 Vb[2][8192];   // [chunk 2][dtile 4][ks2 2][64][8]

  const int tid  = threadIdx.x;
  const int lane = tid & 63;
  const int w    = tid >> 6;
  const int l31  = lane & 31;
  const int b    = blockIdx.y;
  const int seg  = blockIdx.z;
  const int q0w  = blockIdx.x * 128 + w * 32;

  // Q fragments (B operand of S^T = K Q^T): 8 coalesced 1KB loads
  bf16x8 qf[8];
  {
    const bf16* qb = qf_ + ((size_t)(b * 128 + (q0w >> 5)) * 8) * 512 + lane * 8;
    #pragma unroll
    for (int ks = 0; ks < 8; ++ks)
      qf[ks] = *(const bf16x8*)(qb + ks * 512);
  }

  const bf16* ks_p = kf_ + (size_t)b * 128 * 4096 + (size_t)(seg * TPS_) * 8192 + tid * 8;
  const bf16* vs_p = vf_ + (size_t)b * 128 * 4096 + (size_t)(seg * TPS_) * 8192 + tid * 8;

  // prologue: stage tile 0 into buffer 0
  #pragma unroll
  for (int p = 0; p < 4; ++p) {
    gld_lds16(ks_p + p * 2048, &Kb[0][p * 2048 + tid * 8]);
    gld_lds16(vs_p + p * 2048, &Vb[0][p * 2048 + tid * 8]);
  }
  __syncthreads();

  f32x16 o_acc[4];
  #pragma unroll
  for (int dt = 0; dt < 4; ++dt)
    #pragma unroll
    for (int r = 0; r < 16; ++r) o_acc[dt][r] = 0.f;
  f32x16 lacc;
  #pragma unroll
  for (int r = 0; r < 16; ++r) lacc[r] = 0.f;

  const u32x4 onesu = {0x3F803F80u, 0x3F803F80u, 0x3F803F80u, 0x3F803F80u};
  const bf16x8 onesf = __builtin_bit_cast(bf16x8, onesu);

  for (int t = 0; t < TPS_; ++t) {
    const int cur = t & 1;
    // ---- issue next tile's DMA (overlaps with this tile's compute)
    if (t + 1 < TPS_) {
      const bf16* ksn = ks_p + (size_t)(t + 1) * 8192;
      const bf16* vsn = vs_p + (size_t)(t + 1) * 8192;
      #pragma unroll
      for (int p = 0; p < 4; ++p) {
        gld_lds16(ksn + p * 2048, &Kb[cur ^ 1][p * 2048 + tid * 8]);
        gld_lds16(vsn + p * 2048, &Vb[cur ^ 1][p * 2048 + tid * 8]);
      }
    }
    const bf16* Kc = Kb[cur];
    const bf16* Vc = Vb[cur];

    // ---- S^T = K Q^T (exp2 domain), both 32-row halves (2 indep chains)
    f32x16 s0, s1;
    #pragma unroll
    for (int r = 0; r < 16; ++r) { s0[r] = 0.f; s1[r] = 0.f; }
    __builtin_amdgcn_s_setprio(1);
    #pragma unroll
    for (int ks = 0; ks < 8; ++ks) {
      bf16x8 k0 = *(const bf16x8*)&Kc[((0 * 8 + ks) * 64 + lane) * 8];
      bf16x8 k1 = *(const bf16x8*)&Kc[((1 * 8 + ks) * 64 + lane) * 8];
      s0 = mfma32(k0, qf[ks], s0);
      s1 = mfma32(k1, qf[ks], s1);
    }
    __builtin_amdgcn_s_setprio(0);

    // ---- half 0: p = exp2(S' - SHIFT2); pack + permlane32_swap -> pf0, pf1
    bf16x8 pf0, pf1;
    exp_pack(s0, pf0, pf1);

    // ---- PV half 0 (+ l column-sum on matrix pipe)
    __builtin_amdgcn_s_setprio(1);
    #pragma unroll
    for (int dt = 0; dt < 4; ++dt) {
      bf16x8 vf = *(const bf16x8*)&Vc[((dt * 2 + 0) * 64 + lane) * 8];
      o_acc[dt] = mfma32(vf, pf0, o_acc[dt]);
    }
    lacc = mfma32(onesf, pf0, lacc);
    #pragma unroll
    for (int dt = 0; dt < 4; ++dt) {
      bf16x8 vf = *(const bf16x8*)&Vc[((dt * 2 + 1) * 64 + lane) * 8];
      o_acc[dt] = mfma32(vf, pf1, o_acc[dt]);
    }
    lacc = mfma32(onesf, pf1, lacc);
    __builtin_amdgcn_s_setprio(0);

    // ---- half 1 exp/pack (VALU; overlaps PV0 MFMAs across/within waves)
    bf16x8 pf2, pf3;
    exp_pack(s1, pf2, pf3);

    __builtin_amdgcn_s_setprio(1);
    #pragma unroll
    for (int dt = 0; dt < 4; ++dt) {
      bf16x8 vf = *(const bf16x8*)&Vc[4096 + ((dt * 2 + 0) * 64 + lane) * 8];
      o_acc[dt] = mfma32(vf, pf2, o_acc[dt]);
    }
    lacc = mfma32(onesf, pf2, lacc);
    #pragma unroll
    for (int dt = 0; dt < 4; ++dt) {
      bf16x8 vf = *(const bf16x8*)&Vc[4096 + ((dt * 2 + 1) * 64 + lane) * 8];
      o_acc[dt] = mfma32(vf, pf3, o_acc[dt]);
    }
    lacc = mfma32(onesf, pf3, lacc);
    __builtin_amdgcn_s_setprio(0);

    // one barrier per tile: drains next-tile DMA, protects buffers
    __syncthreads();
  }

  // ---- l: all 16 lacc rows identical = sum over this segment; col q = l31
  if (lane < 32)
    lpar[((size_t)seg * B_ + b) * N_ + q0w + lane] = lacc[0];

  // ---- store O^T partials (bf16): col=q=l31, row d = dt*32+R*8+4*(lane>>5)+i
  const int hh = lane >> 5;
  bf16* op = Opar + (((size_t)seg * B_ + b) * N_ + q0w + l31) * C2_;
  #pragma unroll
  for (int dt = 0; dt < 4; ++dt) {
    #pragma unroll
    for (int R = 0; R < 4; ++R) {
      bf16x4 v;
      #pragma unroll
      for (int i = 0; i < 4; ++i) v[i] = (bf16)o_acc[dt][4 * R + i];
      *(bf16x4*)(op + dt * 32 + R * 8 + hh * 4) = v;
    }
  }
}

// ---------------------------------------------------------------------------
// Kernel 3: fused combine + final conv + residual. 64-row n-tiles, 1024
// threads (16 waves = 4 waves/SIMD at 1 block/CU): wave w owns 16 c-rows;
// staging is exactly 1 chunk-task per thread.
// ---------------------------------------------------------------------------
__global__ __launch_bounds__(1024, 4) void final_kernel(
    const float* __restrict__ x, const float* __restrict__ wf,
    const float* __restrict__ bf_,
    const bf16* __restrict__ Opar, const float* __restrict__ lpar,
    float* __restrict__ out)
{
  __shared__ bf16 Ys[64][C2_ + 8];
  __shared__ float Linv[64];

  const int tid  = threadIdx.x;
  const int lane = tid & 63;
  const int w    = tid >> 6;       // 0..15
  const int n0   = blockIdx.x * 64;
  const int b    = blockIdx.y;
  const int l15  = lane & 15;
  const int lg   = lane >> 4;
  const int kbase = lg * 8;

  // ---- 1/l per row
  if (tid < 64) {
    float l = 0.f;
    #pragma unroll
    for (int s = 0; s < SEG_; ++s)
      l += lpar[((size_t)s * B_ + b) * N_ + n0 + tid];
    Linv[tid] = 1.f / l;
  }
  __syncthreads();

  // ---- stage y tile: exactly one 8-elem chunk per thread
  {
    int r   = tid >> 4;
    int c8  = (tid & 15) * 8;
    float a[8] = {0.f, 0.f, 0.f, 0.f, 0.f, 0.f, 0.f, 0.f};
    #pragma unroll
    for (int s = 0; s < SEG_; ++s) {
      bf16x8 v = *(const bf16x8*)(Opar
          + (((size_t)s * B_ + b) * N_ + n0 + r) * C2_ + c8);
      #pragma unroll
      for (int j = 0; j < 8; ++j) a[j] += (float)v[j];
    }
    float inv = Linv[r];
    bf16x8 y;
    #pragma unroll
    for (int j = 0; j < 8; ++j) y[j] = (bf16)(a[j] * inv);
    *(bf16x8*)&Ys[r][c8] = y;
  }
  __syncthreads();

  // ---- GEMM: wave w owns c-rows [16w, 16w+16)
  const f32x4 fzero = {0.f, 0.f, 0.f, 0.f};
  f32x4 acc[4];
  #pragma unroll
  for (int ct = 0; ct < 4; ++ct) acc[ct] = fzero;

  for (int kc = 0; kc < 4; ++kc) {
    bf16x8 bfr[4];
    #pragma unroll
    for (int ct = 0; ct < 4; ++ct)
      bfr[ct] = *(const bf16x8*)&Ys[ct * 16 + l15][kc * 32 + kbase];
    const float* wr = wf + (size_t)(w * 16 + l15) * C2_ + kc * 32 + kbase;
    f32x4 lo = *(const f32x4*)wr;
    f32x4 hi = *(const f32x4*)(wr + 4);
    bf16x8 af;
    #pragma unroll
    for (int i = 0; i < 4; ++i) { af[i] = (bf16)lo[i]; af[4 + i] = (bf16)hi[i]; }
    #pragma unroll
    for (int ct = 0; ct < 4; ++ct)
      acc[ct] = mfma16(af, bfr[ct], acc[ct]);
  }

  {
    int cbase = w * 16 + lg * 4;
    #pragma unroll
    for (int j = 0; j < 4; ++j) {
      float bias = bf_[cbase + j];
      #pragma unroll
      for (int ct = 0; ct < 4; ++ct) {
        int n = n0 + ct * 16 + l15;
        size_t idx = ((size_t)b * C_ + cbase + j) * N_ + n;
        out[idx] = x[idx] + bias + acc[ct][j];
      }
    }
  }
}

// ---------------------------------------------------------------------------
extern "C" void kernel_launch(void* const* d_in, const int* in_sizes, int n_in,
                              void* d_out, int out_size, void* d_ws, size_t ws_size,
                              hipStream_t stream) {
  const float* x       = (const float*)d_in[0];
  const float* w_theta = (const float*)d_in[1];
  const float* b_theta = (const float*)d_in[2];
  const float* w_phi   = (const float*)d_in[3];
  const float* b_phi   = (const float*)d_in[4];
  const float* w_g     = (const float*)d_in[5];
  const float* b_g     = (const float*)d_in[6];
  const float* w_final = (const float*)d_in[7];
  const float* b_final = (const float*)d_in[8];
  float* out = (float*)d_out;

  char* ws = (char*)d_ws;
  const size_t SZB = (size_t)B_ * N_ * C2_ * sizeof(bf16);   // 4 MB each
  bf16*  th = (bf16*)(ws);
  bf16*  ph = (bf16*)(ws + SZB);
  bf16*  gt = (bf16*)(ws + 2 * SZB);
  bf16*  OparB = (bf16*)(ws + 3 * SZB);                      // SEG_ x 4 MB (bf16)
  float* lpar  = (float*)(ws + 3 * SZB + SEG_ * SZB);        // 256 KB

  proj_kernel<<<dim3(N_ / 64, B_), 768, 0, stream>>>(
      x, w_theta, b_theta, w_phi, b_phi, w_g, b_g, th, ph, gt);
  attn_kernel<<<dim3(N_ / 128, B_, SEG_), 256, 0, stream>>>(
      th, ph, gt, OparB, lpar);
  final_kernel<<<dim3(N_ / 64, B_), 1024, 0, stream>>>(
      x, w_final, b_final, OparB, lpar, out);
}